// Round 7
// baseline (250.381 us; speedup 1.0000x reference)
//
#include <hip/hip_runtime.h>
#include <hip/hip_bf16.h>
#include <math.h>

typedef __bf16 bf16;
typedef __bf16 bf16x8 __attribute__((ext_vector_type(8)));
typedef float f32x4 __attribute__((ext_vector_type(4)));
typedef float f32x16 __attribute__((ext_vector_type(16)));
typedef unsigned u32x4 __attribute__((ext_vector_type(4)));

#define MFMA16(a, b, c) __builtin_amdgcn_mfma_f32_16x16x32_bf16((a), (b), (c), 0, 0, 0)
#define MFMA32(a, b, c) __builtin_amdgcn_mfma_f32_32x32x16_bf16((a), (b), (c), 0, 0, 0)

// async global->LDS, 16B per lane. LDS dest = wave-uniform base + lane*16.
__device__ __forceinline__ void gl_lds16(const void* g, void* l) {
    __builtin_amdgcn_global_load_lds(
        (__attribute__((address_space(1))) void*)(g),
        (__attribute__((address_space(3))) void*)(l),
        16, 0, 0);
}

__device__ __forceinline__ unsigned cvt_pk_bf16(float lo, float hi) {
    unsigned r;
    asm("v_cvt_pk_bf16_f32 %0, %1, %2" : "=v"(r) : "v"(lo), "v"(hi));
    return r;
}

// ---------------------------------------------------------------------------
// fp32 -> bf16 conversion: 4 weights (1M) + optionally 3 token tensors (4M).
// ---------------------------------------------------------------------------
__global__ __launch_bounds__(256) void cvt7(
    const float* __restrict__ w0, const float* __restrict__ w1,
    const float* __restrict__ w2, const float* __restrict__ w3,
    const float* __restrict__ x0, const float* __restrict__ x1,
    const float* __restrict__ x2, bf16* __restrict__ dst) {
    const int z = blockIdx.y;
    const float* src;
    bf16* out;
    if (z < 4) {
        if (blockIdx.x >= 512) return;
        src = (z == 0) ? w0 : (z == 1) ? w1 : (z == 2) ? w2 : w3;
        out = dst + (size_t)z * 1048576;
    } else {
        src = (z == 4) ? x0 : (z == 5) ? x1 : x2;
        out = dst + 4 * 1048576 + (size_t)(z - 4) * 4194304;
    }
    const int i = (blockIdx.x * 256 + threadIdx.x) * 8;
    float4 a = ((const float4*)(src + i))[0];
    float4 b = ((const float4*)(src + i))[1];
    bf16x8 o;
    o[0] = (bf16)a.x; o[1] = (bf16)a.y; o[2] = (bf16)a.z; o[3] = (bf16)a.w;
    o[4] = (bf16)b.x; o[5] = (bf16)b.y; o[6] = (bf16)b.z; o[7] = (bf16)b.w;
    *(bf16x8*)(out + i) = o;
}

// ---------------------------------------------------------------------------
// Pure-bf16 GEMM, BK=64, T2 both-sides XOR swizzle (rule #21): LDS dest
// linear (gl_lds16 requires it), global SOURCE chunk pre-swizzled
// cg^(row&7), frag reads apply the same XOR -> all reads exactly 2-way
// bank aliased (free). Accumulation order identical to BK=32.
// EP 0: scatter bf16 -> [B,H,S,dk]   EP 1: fp32 [M,1024]   EP 2: V^T [B,H,dk,S]
// ---------------------------------------------------------------------------
template <int EP>
__device__ __forceinline__ void gemm_bf(const bf16* __restrict__ A,
                                        const bf16* __restrict__ B,
                                        void* __restrict__ Cv,
                                        const int m0, const int n0) {
    constexpr int K = 1024;
    __shared__ __align__(16) bf16 As[128 * 64];
    __shared__ __align__(16) bf16 Bs[128 * 64];

    const int t = threadIdx.x;
    const int lane = t & 63;
    const int w = t >> 6;
    const int wm = (w & 1) * 64;
    const int wn = (w >> 1) * 64;
    const int lr = lane & 15;
    const int rq = (lane >> 4) * 4;
    const int ch0 = lane >> 4;        // frag base chunk (lq8/8)
    const int lsw = lr & 7;           // frag-read swizzle

    f32x4 acc[4][4] = {};

    const int srow = t >> 3;          // 0..31
    const int scg = ((t & 7) ^ (srow & 7)) * 8;   // pre-swizzled source chunk
    char* lA = (char*)As;
    char* lB = (char*)Bs;

    for (int k0 = 0; k0 < K; k0 += 64) {
#pragma unroll
        for (int i = 0; i < 4; ++i) {
            gl_lds16(A + (size_t)(m0 + i * 32 + srow) * K + k0 + scg, lA + i * 4096 + t * 16);
            gl_lds16(B + (size_t)(n0 + i * 32 + srow) * K + k0 + scg, lB + i * 4096 + t * 16);
        }
        __syncthreads();

#pragma unroll
        for (int kk = 0; kk < 64; kk += 32) {
            bf16x8 af[4], bfr[4];
#pragma unroll
            for (int i = 0; i < 4; ++i) {
                const int ro = (wm + i * 16 + lr) * 64 + ((((kk >> 3) + ch0) ^ lsw) * 8);
                const int co = (wn + i * 16 + lr) * 64 + ((((kk >> 3) + ch0) ^ lsw) * 8);
                af[i]  = *(const bf16x8*)&As[ro];
                bfr[i] = *(const bf16x8*)&Bs[co];
            }
#pragma unroll
            for (int mi = 0; mi < 4; ++mi)
#pragma unroll
                for (int ni = 0; ni < 4; ++ni)
                    acc[mi][ni] = MFMA16(af[mi], bfr[ni], acc[mi][ni]);
        }
        __syncthreads();
    }

#pragma unroll
    for (int mi = 0; mi < 4; ++mi) {
#pragma unroll
        for (int ni = 0; ni < 4; ++ni) {
#pragma unroll
            for (int r = 0; r < 4; ++r) {
                const int m = m0 + wm + mi * 16 + rq + r;
                const int n = n0 + wn + ni * 16 + lr;
                const float vv = acc[mi][ni][r];
                if constexpr (EP == 0) {
                    bf16* C = (bf16*)Cv;
                    const int b = m >> 11, s = m & 2047;
                    const int h = n >> 6,  d = n & 63;
                    C[(((size_t)(b * 16 + h)) * 2048 + s) * 64 + d] = (bf16)vv;
                } else if constexpr (EP == 1) {
                    float* C = (float*)Cv;
                    C[(size_t)m * 1024 + n] = vv;
                } else {
                    bf16* C = (bf16*)Cv;   // V^T: [b][h*64+d=m][s=n&2047]
                    C[((size_t)(n >> 11) * 1024 + m) * 2048 + (n & 2047)] = (bf16)vv;
                }
            }
        }
    }
}

// 768 blocks = 3/CU single pass at (256,3). LDS 32KB x3 = 96KB <= 160KB.
__global__ __launch_bounds__(256, 3) void qkv_bf(
    const bf16* __restrict__ Xq, const bf16* __restrict__ Xk,
    const bf16* __restrict__ Xv, const bf16* __restrict__ Wc,
    bf16* __restrict__ Qb, bf16* __restrict__ Kb, bf16* __restrict__ Vb) {
    const int z = blockIdx.z;
    if (z == 0)
        gemm_bf<0>(Xq, Wc, Qb, blockIdx.x * 128, blockIdx.y * 128);
    else if (z == 1)
        gemm_bf<0>(Xk, Wc + 1048576, Kb, blockIdx.x * 128, blockIdx.y * 128);
    else
        gemm_bf<2>(Wc + 2 * 1048576, Xv, Vb, blockIdx.y * 128, blockIdx.x * 128);
}

// ---------------------------------------------------------------------------
// out GEMM: 256 blocks, 512 threads / 8 waves (2 waves/SIMD), wave-tile
// 64x32, BK=64, same T2 swizzle as gemm_bf.
// ---------------------------------------------------------------------------
__global__ __launch_bounds__(512, 2) void out_gemm(
    const bf16* __restrict__ X, const bf16* __restrict__ W, float* __restrict__ C) {
    constexpr int K = 1024;
    __shared__ __align__(16) bf16 As[128 * 64];
    __shared__ __align__(16) bf16 Bs[128 * 64];

    const int t = threadIdx.x;
    const int lane = t & 63;
    const int w = t >> 6;            // 0..7
    const int wm = (w >> 2) * 64;    // 2 m-groups
    const int wn = (w & 3) * 32;     // 4 n-groups
    const int lr = lane & 15;
    const int rq = (lane >> 4) * 4;
    const int ch0 = lane >> 4;
    const int lsw = lr & 7;
    const int m0 = blockIdx.x * 128, n0 = blockIdx.y * 128;

    f32x4 acc[4][2] = {};

    const int srow = t >> 3;         // 0..63
    const int scg = ((t & 7) ^ (srow & 7)) * 8;
    char* lA = (char*)As;
    char* lB = (char*)Bs;

    for (int k0 = 0; k0 < K; k0 += 64) {
#pragma unroll
        for (int i = 0; i < 2; ++i) {
            gl_lds16(X + (size_t)(m0 + i * 64 + srow) * K + k0 + scg, lA + i * 8192 + t * 16);
            gl_lds16(W + (size_t)(n0 + i * 64 + srow) * K + k0 + scg, lB + i * 8192 + t * 16);
        }
        __syncthreads();

#pragma unroll
        for (int kk = 0; kk < 64; kk += 32) {
            bf16x8 af[4], bfr[2];
#pragma unroll
            for (int i = 0; i < 4; ++i)
                af[i] = *(const bf16x8*)&As[(wm + i * 16 + lr) * 64 + ((((kk >> 3) + ch0) ^ lsw) * 8)];
#pragma unroll
            for (int i = 0; i < 2; ++i)
                bfr[i] = *(const bf16x8*)&Bs[(wn + i * 16 + lr) * 64 + ((((kk >> 3) + ch0) ^ lsw) * 8)];
#pragma unroll
            for (int mi = 0; mi < 4; ++mi)
#pragma unroll
                for (int ni = 0; ni < 2; ++ni)
                    acc[mi][ni] = MFMA16(af[mi], bfr[ni], acc[mi][ni]);
        }
        __syncthreads();
    }

#pragma unroll
    for (int mi = 0; mi < 4; ++mi)
#pragma unroll
        for (int ni = 0; ni < 2; ++ni)
#pragma unroll
            for (int r = 0; r < 4; ++r) {
                const int m = m0 + wm + mi * 16 + rq + r;
                const int n = n0 + wn + ni * 16 + lr;
                C[(size_t)m * 1024 + n] = acc[mi][ni][r];
            }
}

// ---------------------------------------------------------------------------
// Fallback qkv (fp32 tokens staged in-register) for small workspaces.
// ---------------------------------------------------------------------------
template <int MODE>
__device__ __forceinline__ void gemm_f32tok(const void* __restrict__ Av,
                                            const void* __restrict__ Bv,
                                            bf16* __restrict__ C,
                                            const int m0, const int n0) {
    constexpr int K = 1024;
    __shared__ __align__(16) bf16 As[128 * 32];
    __shared__ __align__(16) bf16 Bs[128 * 32];

    const int t = threadIdx.x;
    const int lane = t & 63;
    const int w = t >> 6;
    const int wm = (w & 1) * 64;
    const int wn = (w >> 1) * 64;
    const int lr = lane & 15;
    const int lq8 = (lane >> 4) * 8;
    const int rq = (lane >> 4) * 4;

    f32x4 acc[4][4] = {};
    const int srow = t >> 2;
    const int sch = (t & 3) * 8;
    const int ar = t >> 1;
    const int ac = (t & 1) * 16;
    char* lA = (char*)As;
    char* lB = (char*)Bs;

    for (int k0 = 0; k0 < K; k0 += 32) {
        if constexpr (MODE == 0) {
            const float* X = (const float*)Av;
            const float* p = X + (size_t)(m0 + ar) * K + k0 + ac;
            float4 f0 = ((const float4*)p)[0], f1 = ((const float4*)p)[1];
            float4 f2 = ((const float4*)p)[2], f3 = ((const float4*)p)[3];
            bf16x8 o0, o1;
            o0[0]=(bf16)f0.x; o0[1]=(bf16)f0.y; o0[2]=(bf16)f0.z; o0[3]=(bf16)f0.w;
            o0[4]=(bf16)f1.x; o0[5]=(bf16)f1.y; o0[6]=(bf16)f1.z; o0[7]=(bf16)f1.w;
            o1[0]=(bf16)f2.x; o1[1]=(bf16)f2.y; o1[2]=(bf16)f2.z; o1[3]=(bf16)f2.w;
            o1[4]=(bf16)f3.x; o1[5]=(bf16)f3.y; o1[6]=(bf16)f3.z; o1[7]=(bf16)f3.w;
            *(bf16x8*)&As[ar * 32 + ac]     = o0;
            *(bf16x8*)&As[ar * 32 + ac + 8] = o1;
        } else {
            const bf16* X = (const bf16*)Av;
            gl_lds16(X + (size_t)(m0 + srow) * K + k0 + sch,      lA + t * 16);
            gl_lds16(X + (size_t)(m0 + 64 + srow) * K + k0 + sch, lA + 4096 + t * 16);
        }
        if constexpr (MODE == 2) {
            const float* X = (const float*)Bv;
            const float* p = X + (size_t)(n0 + ar) * K + k0 + ac;
            float4 f0 = ((const float4*)p)[0], f1 = ((const float4*)p)[1];
            float4 f2 = ((const float4*)p)[2], f3 = ((const float4*)p)[3];
            bf16x8 o0, o1;
            o0[0]=(bf16)f0.x; o0[1]=(bf16)f0.y; o0[2]=(bf16)f0.z; o0[3]=(bf16)f0.w;
            o0[4]=(bf16)f1.x; o0[5]=(bf16)f1.y; o0[6]=(bf16)f1.z; o0[7]=(bf16)f1.w;
            o1[0]=(bf16)f2.x; o1[1]=(bf16)f2.y; o1[2]=(bf16)f2.z; o1[3]=(bf16)f2.w;
            o1[4]=(bf16)f3.x; o1[5]=(bf16)f3.y; o1[6]=(bf16)f3.z; o1[7]=(bf16)f3.w;
            *(bf16x8*)&Bs[ar * 32 + ac]     = o0;
            *(bf16x8*)&Bs[ar * 32 + ac + 8] = o1;
        } else {
            const bf16* W = (const bf16*)Bv;
            gl_lds16(W + (size_t)(n0 + srow) * K + k0 + sch,      lB + t * 16);
            gl_lds16(W + (size_t)(n0 + 64 + srow) * K + k0 + sch, lB + 4096 + t * 16);
        }
        __syncthreads();

        bf16x8 af[4], bfr[4];
#pragma unroll
        for (int i = 0; i < 4; ++i) {
            af[i]  = *(const bf16x8*)&As[(wm + i * 16 + lr) * 32 + lq8];
            bfr[i] = *(const bf16x8*)&Bs[(wn + i * 16 + lr) * 32 + lq8];
        }
#pragma unroll
        for (int mi = 0; mi < 4; ++mi)
#pragma unroll
            for (int ni = 0; ni < 4; ++ni)
                acc[mi][ni] = MFMA16(af[mi], bfr[ni], acc[mi][ni]);
        __syncthreads();
    }

#pragma unroll
    for (int mi = 0; mi < 4; ++mi) {
#pragma unroll
        for (int ni = 0; ni < 4; ++ni) {
#pragma unroll
            for (int r = 0; r < 4; ++r) {
                const int m = m0 + wm + mi * 16 + rq + r;
                const int n = n0 + wn + ni * 16 + lr;
                const float vv = acc[mi][ni][r];
                if constexpr (MODE == 0) {
                    const int b = m >> 11, s = m & 2047;
                    const int h = n >> 6,  d = n & 63;
                    C[(((size_t)(b * 16 + h)) * 2048 + s) * 64 + d] = (bf16)vv;
                } else {
                    C[((size_t)(n >> 11) * 1024 + m) * 2048 + (n & 2047)] = (bf16)vv;
                }
            }
        }
    }
}

__global__ __launch_bounds__(256, 2) void qkv_f32(
    const float* __restrict__ q, const float* __restrict__ k, const float* __restrict__ v,
    const bf16* __restrict__ Wc, bf16* __restrict__ Qb, bf16* __restrict__ Kb,
    bf16* __restrict__ Vb) {
    const int z = blockIdx.z;
    if (z == 0)
        gemm_f32tok<0>(q, Wc, Qb, blockIdx.x * 128, blockIdx.y * 128);
    else if (z == 1)
        gemm_f32tok<0>(k, Wc + 1048576, Kb, blockIdx.x * 128, blockIdx.y * 128);
    else
        gemm_f32tok<2>(Wc + 2 * 1048576, v, Vb, blockIdx.y * 128, blockIdx.x * 128);
}

// ---------------------------------------------------------------------------
// Fused flash attention v8: v6 inner loop (proven 61.7us) at 4 waves/SIMD.
// Block = 4 waves: wg = w&1 owns a 32-q tile, kh = w>>1 owns a key half.
// Grid 1024 = 4 blocks/CU -> 16 waves/CU = 4 waves/SIMD (v6 had ~2.5, v7 2;
// measured: duration tracks resident waves, not per-wave LDS traffic ->
// dependency-latency bound). Prefetch right after barrier B (T14). MFMA
// zero-init via C-operand (no per-iter v_mov block). No setprio (R5: -26%).
// Fixed-max softmax; halves merge by addition via one LDS swap (stride 33).
// XCD-pinned head decode (lin%8).
// ---------------------------------------------------------------------------
__global__ __launch_bounds__(256, 4) void attn_kernel(
    const bf16* __restrict__ Qb, const bf16* __restrict__ Kb,
    const bf16* __restrict__ Vb, bf16* __restrict__ Xb) {
    constexpr int S = 2048;

    // staging: K half kh at [kh*4096], V half kh at [8192+kh*4096] (elems)
    // epilogue swap area: 4224 f32 = 16896 B (reuses staging region)
    __shared__ __align__(16) bf16 smem[17408];

    const int t = threadIdx.x;         // 0..255
    const int lane = t & 63;
    const int w = t >> 6;              // 0..3
    const int wg = w & 1;              // q-tile within block
    const int kh = w >> 1;             // key half
    const int l31 = lane & 31;
    const int half = lane >> 5;

    // XCD-aware decode: head pinned to lin%8; 32 q-blocks (64 q each) per head
    const int lin = blockIdx.x;        // 0..1023
    const int g = lin >> 3;            // 0..127
    const int bh = (lin & 7) + 8 * (g & 3);
    const int q0 = (g >> 2) * 64 + wg * 32;

    const bf16* Q  = Qb + (size_t)bh * S * 64;   // [s][d]
    const bf16* Kh = Kb + (size_t)bh * S * 64;   // [s][d]
    const bf16* Vh = Vb + (size_t)bh * 64 * S;   // [d][s]

    // Q fragments in registers (B operand), scaled into log2 domain.
    const float qscale = 0.125f * 1.4426950408889634f;
    bf16x8 qf[4];
#pragma unroll
    for (int c = 0; c < 4; ++c) {
        bf16x8 v0 = *(const bf16x8*)(Q + (size_t)(q0 + l31) * 64 + c * 16 + half * 8);
#pragma unroll
        for (int e = 0; e < 8; ++e) v0[e] = (bf16)((float)v0[e] * qscale);
        qf[c] = v0;
    }

    f32x16 od[2] = {};                 // O[q(reg-pattern)][d = dt*32 + l31]
    float ls0 = 0.f, ls1 = 0.f, ls2 = 0.f, ls3 = 0.f;

    // staging: 128 threads per kh half, 4 chunks (16B) per tensor each.
    const int tt = t & 127;
    const int sr = tt >> 1;            // key (K) / d (V), 0..63
    const int scb = (tt & 1) * 4;      // chunk base 0 or 4
    const bf16* pKg = Kh + ((size_t)kh * 1024 + sr) * 64 + scb * 8;   // += 4096/tile
    const bf16* pVg = Vh + (size_t)sr * S + kh * 1024 + scb * 8;      // += 64/tile
    bf16* KsH = smem + kh * 4096;
    bf16* VsH = smem + 8192 + kh * 4096;
    int wKo[4];
#pragma unroll
    for (int c = 0; c < 4; ++c)
        wKo[c] = (sr >> 1) * 128 + ((((sr & 1) << 3) + scb + c) ^ ((sr >> 1) & 15)) * 8;

    bf16x8 pk[4], pv[4];
#pragma unroll
    for (int c = 0; c < 4; ++c) {
        pk[c] = *(const bf16x8*)(pKg + c * 8);
        pv[c] = *(const bf16x8*)(pVg + c * 8);
    }

    // frag-read address helpers (elements)
    const int fbase = (l31 >> 1) * 128;
    const int fb8 = (l31 & 1) << 3;
    const int fsw = l31 >> 1;

    const f32x16 fz = {};

    for (int j = 0; j < 16; ++j) {
        __syncthreads();  // (A) prev tile's reads done
#pragma unroll
        for (int c = 0; c < 4; ++c) {
            *(bf16x8*)&KsH[wKo[c]] = pk[c];
            *(bf16x8*)&VsH[wKo[c]] = pv[c];
        }
        __syncthreads();  // (B) staging visible

        // issue next tile's global loads now (T14): latency hides under compute
        if (j + 1 < 16) {
            pKg += 4096;
            pVg += 64;
#pragma unroll
            for (int c = 0; c < 4; ++c) {
                pk[c] = *(const bf16x8*)(pKg + c * 8);
                pv[c] = *(const bf16x8*)(pVg + c * 8);
            }
        }

#pragma unroll
        for (int kt = 0; kt < 2; ++kt) {
            // swapped QK^T: s = K-tile(kt) x Q  ->  P[q=l31][k=reg-pattern]
            bf16x8 kf[4];
#pragma unroll
            for (int c = 0; c < 4; ++c)
                kf[c] = *(const bf16x8*)
                    &KsH[kt * 2048 + fbase + ((fb8 + c * 2 + half) ^ fsw) * 8];
            f32x16 s = MFMA32(kf[0], qf[0], fz);
#pragma unroll
            for (int c = 1; c < 4; ++c)
                s = MFMA32(kf[c], qf[c], s);

            // exp2 in-register, l accumulate
            float ex[16];
#pragma unroll
            for (int r = 0; r < 16; ++r)
                ex[r] = exp2f(s[r]);
            ls0 += ex[0] + ex[4] + ex[8]  + ex[12];
            ls1 += ex[1] + ex[5] + ex[9]  + ex[13];
            ls2 += ex[2] + ex[6] + ex[10] + ex[14];
            ls3 += ex[3] + ex[7] + ex[11] + ex[15];

            // T12: pa holds P[q=l31][key = khbase + kt*32 + c2*16 + half*8 + 0..7]
            unsigned pa[8];
#pragma unroll
            for (int c2 = 0; c2 < 2; ++c2) {
#pragma unroll
                for (int wd = 0; wd < 2; ++wd) {
                    unsigned x = cvt_pk_bf16(ex[c2 * 8 + wd * 2 + 0], ex[c2 * 8 + wd * 2 + 1]);
                    unsigned y = cvt_pk_bf16(ex[c2 * 8 + wd * 2 + 4], ex[c2 * 8 + wd * 2 + 5]);
                    asm("v_permlane32_swap_b32 %0, %1" : "+v"(x), "+v"(y));
                    pa[c2 * 4 + wd]     = x;
                    pa[c2 * 4 + wd + 2] = y;
                }
            }

            // PV: O[dt] += P(keys kt*32+c2*16) @ V^T rows dt*32+l31
#pragma unroll
            for (int c2 = 0; c2 < 2; ++c2) {
                u32x4 aw;
                aw[0] = pa[c2 * 4 + 0]; aw[1] = pa[c2 * 4 + 1];
                aw[2] = pa[c2 * 4 + 2]; aw[3] = pa[c2 * 4 + 3];
                bf16x8 ap = __builtin_bit_cast(bf16x8, aw);
#pragma unroll
                for (int dt = 0; dt < 2; ++dt) {
                    const int cgv = kt * 4 + c2 * 2 + half;
                    bf16x8 vf = *(const bf16x8*)
                        &VsH[dt * 2048 + fbase + ((fb8 + cgv) ^ fsw) * 8];
                    od[dt] = MFMA32(ap, vf, od[dt]);
                }
            }
        }
    }

    // ---- merge the two key halves ----
    float lsum = ls0 + ls1 + ls2 + ls3;
    float ltot = lsum + __shfl_xor(lsum, 32);   // per q=l31, this wave's keys

    __syncthreads();  // all PV LDS reads done before swap overwrite
    float* fsm = (float*)smem;
    const int so = (wg * 64 + lane) * 33;
    if (kh == 1) {
        fsm[so + 32] = ltot;
#pragma unroll
        for (int r = 0; r < 16; ++r) {
            fsm[so + r]      = od[0][r];
            fsm[so + 16 + r] = od[1][r];
        }
    }
    __syncthreads();
    if (kh == 0) {
        ltot += fsm[so + 32];
        const float inv = 1.f / fmaxf(ltot, 1e-30f);   // lane L: q = L&31
        const int b = bh >> 4, hh = bh & 15;
#pragma unroll
        for (int r = 0; r < 16; ++r) {
            const int qrow = (r & 3) + 8 * (r >> 2) + 4 * half;
            const float invr = __shfl(inv, qrow);
            const size_t base = ((size_t)(b * 2048 + q0 + qrow)) * 1024 + hh * 64;
            Xb[base + l31]      = (bf16)((od[0][r] + fsm[so + r]) * invr);
            Xb[base + 32 + l31] = (bf16)((od[1][r] + fsm[so + 16 + r]) * invr);
        }
    }
}

extern "C" void kernel_launch(void* const* d_in, const int* in_sizes, int n_in,
                              void* d_out, int out_size, void* d_ws, size_t ws_size,
                              hipStream_t stream) {
    const float* q  = (const float*)d_in[0];
    const float* k  = (const float*)d_in[1];
    const float* v  = (const float*)d_in[2];
    const float* wq = (const float*)d_in[4];
    const float* wk = (const float*)d_in[5];
    const float* wv = (const float*)d_in[6];
    const float* wo = (const float*)d_in[7];
    float* out = (float*)d_out;

    const bool big = ws_size >= (size_t)64 * 1024 * 1024;
    bf16* Wc = (bf16*)d_ws;
    const dim3 blk(256);

    if (big) {
        bf16* Xq = Wc + 4 * 1048576;
        bf16* Xk = Xq + 4194304;
        bf16* Xv = Xk + 4194304;
        bf16* Qb = Xv + 4194304;
        bf16* Kb = Qb + 4194304;
        bf16* Vb = Kb + 4194304;          // [2,16,64,2048] (V^T)
        bf16* Xb = Vb + 4194304;
        cvt7<<<dim3(2048, 7), blk, 0, stream>>>(wq, wk, wv, wo, q, k, v, Wc);
        qkv_bf<<<dim3(32, 8, 3), blk, 0, stream>>>(Xq, Xk, Xv, Wc, Qb, Kb, Vb);
        attn_kernel<<<dim3(1024), dim3(256), 0, stream>>>(Qb, Kb, Vb, Xb);
        out_gemm<<<dim3(32, 8), dim3(512), 0, stream>>>(Xb, Wc + 3 * 1048576, out);
    } else {
        bf16* Qb = Wc + 4 * 1048576;
        bf16* Kb = Qb + 4194304;
        bf16* Vb = Kb + 4194304;
        bf16* Xb = Vb + 4194304;
        cvt7<<<dim3(512, 4), blk, 0, stream>>>(wq, wk, wv, wo, q, k, v, Wc);
        qkv_f32<<<dim3(32, 8, 3), blk, 0, stream>>>(q, k, v, Wc, Qb, Kb, Vb);
        attn_kernel<<<dim3(1024), dim3(256), 0, stream>>>(Qb, Kb, Vb, Xb);
        out_gemm<<<dim3(32, 8), dim3(512), 0, stream>>>(Xb, Wc + 3 * 1048576, out);
    }
}

// Round 8
// 243.390 us; speedup vs baseline: 1.0287x; 1.0287x over previous
//
#include <hip/hip_runtime.h>
#include <hip/hip_bf16.h>
#include <math.h>

typedef __bf16 bf16;
typedef __bf16 bf16x8 __attribute__((ext_vector_type(8)));
typedef float f32x4 __attribute__((ext_vector_type(4)));
typedef float f32x16 __attribute__((ext_vector_type(16)));
typedef unsigned u32x4 __attribute__((ext_vector_type(4)));

#define MFMA16(a, b, c) __builtin_amdgcn_mfma_f32_16x16x32_bf16((a), (b), (c), 0, 0, 0)
#define MFMA32(a, b, c) __builtin_amdgcn_mfma_f32_32x32x16_bf16((a), (b), (c), 0, 0, 0)

// async global->LDS, 16B per lane. LDS dest = wave-uniform base + lane*16.
__device__ __forceinline__ void gl_lds16(const void* g, void* l) {
    __builtin_amdgcn_global_load_lds(
        (__attribute__((address_space(1))) void*)(g),
        (__attribute__((address_space(3))) void*)(l),
        16, 0, 0);
}

__device__ __forceinline__ unsigned cvt_pk_bf16(float lo, float hi) {
    unsigned r;
    asm("v_cvt_pk_bf16_f32 %0, %1, %2" : "=v"(r) : "v"(lo), "v"(hi));
    return r;
}

// ---------------------------------------------------------------------------
// fp32 -> bf16 conversion: 4 weights (1M) + optionally 3 token tensors (4M).
// ---------------------------------------------------------------------------
__global__ __launch_bounds__(256) void cvt7(
    const float* __restrict__ w0, const float* __restrict__ w1,
    const float* __restrict__ w2, const float* __restrict__ w3,
    const float* __restrict__ x0, const float* __restrict__ x1,
    const float* __restrict__ x2, bf16* __restrict__ dst) {
    const int z = blockIdx.y;
    const float* src;
    bf16* out;
    if (z < 4) {
        if (blockIdx.x >= 512) return;
        src = (z == 0) ? w0 : (z == 1) ? w1 : (z == 2) ? w2 : w3;
        out = dst + (size_t)z * 1048576;
    } else {
        src = (z == 4) ? x0 : (z == 5) ? x1 : x2;
        out = dst + 4 * 1048576 + (size_t)(z - 4) * 4194304;
    }
    const int i = (blockIdx.x * 256 + threadIdx.x) * 8;
    float4 a = ((const float4*)(src + i))[0];
    float4 b = ((const float4*)(src + i))[1];
    bf16x8 o;
    o[0] = (bf16)a.x; o[1] = (bf16)a.y; o[2] = (bf16)a.z; o[3] = (bf16)a.w;
    o[4] = (bf16)b.x; o[5] = (bf16)b.y; o[6] = (bf16)b.z; o[7] = (bf16)b.w;
    *(bf16x8*)(out + i) = o;
}

// ---------------------------------------------------------------------------
// Pure-bf16 GEMM, BK=32, T3 2-phase double-buffer: stage NEXT k-tile (async
// gl_lds16), compute CURRENT, ONE barrier/iter (drain covers the staged
// loads with the compute phase, not an exposed stall). LDS 2x16KB = 32KB ->
// still 3 blocks/CU. Accumulation order identical -> bit-identical results.
// EP 0: scatter bf16 -> [B,H,S,dk]   EP 1: fp32 [M,1024]   EP 2: V^T [B,H,dk,S]
// ---------------------------------------------------------------------------
template <int EP>
__device__ __forceinline__ void gemm_bf(const bf16* __restrict__ A,
                                        const bf16* __restrict__ B,
                                        void* __restrict__ Cv,
                                        const int m0, const int n0) {
    constexpr int K = 1024;
    __shared__ __align__(16) bf16 As[2][128 * 32];
    __shared__ __align__(16) bf16 Bs[2][128 * 32];

    const int t = threadIdx.x;
    const int lane = t & 63;
    const int w = t >> 6;
    const int wm = (w & 1) * 64;
    const int wn = (w >> 1) * 64;
    const int lr = lane & 15;
    const int lq8 = (lane >> 4) * 8;
    const int rq = (lane >> 4) * 4;

    f32x4 acc[4][4] = {};

    const int srow = t >> 2;
    const int sch = (t & 3) * 8;
    char* lA = (char*)As;
    char* lB = (char*)Bs;

#define QSTAGE(buf, k0)                                                              \
    do {                                                                             \
        gl_lds16(A + (size_t)(m0 + srow) * K + (k0) + sch,                           \
                 lA + (buf) * 8192 + t * 16);                                        \
        gl_lds16(A + (size_t)(m0 + 64 + srow) * K + (k0) + sch,                      \
                 lA + (buf) * 8192 + 4096 + t * 16);                                 \
        gl_lds16(B + (size_t)(n0 + srow) * K + (k0) + sch,                           \
                 lB + (buf) * 8192 + t * 16);                                        \
        gl_lds16(B + (size_t)(n0 + 64 + srow) * K + (k0) + sch,                      \
                 lB + (buf) * 8192 + 4096 + t * 16);                                 \
    } while (0)

    QSTAGE(0, 0);
    __syncthreads();   // buf0 ready

    int cur = 0;
    for (int k0 = 0; k0 < K; k0 += 32) {
        if (k0 + 32 < K) QSTAGE(cur ^ 1, k0 + 32);  // async, hidden by compute

        bf16x8 af[4], bfr[4];
#pragma unroll
        for (int i = 0; i < 4; ++i) {
            af[i]  = *(const bf16x8*)&As[cur][(wm + i * 16 + lr) * 32 + lq8];
            bfr[i] = *(const bf16x8*)&Bs[cur][(wn + i * 16 + lr) * 32 + lq8];
        }
#pragma unroll
        for (int mi = 0; mi < 4; ++mi)
#pragma unroll
            for (int ni = 0; ni < 4; ++ni)
                acc[mi][ni] = MFMA16(af[mi], bfr[ni], acc[mi][ni]);

        __syncthreads();   // drains staged loads + all reads of cur done
        cur ^= 1;
    }
#undef QSTAGE

#pragma unroll
    for (int mi = 0; mi < 4; ++mi) {
#pragma unroll
        for (int ni = 0; ni < 4; ++ni) {
#pragma unroll
            for (int r = 0; r < 4; ++r) {
                const int m = m0 + wm + mi * 16 + rq + r;
                const int n = n0 + wn + ni * 16 + lr;
                const float vv = acc[mi][ni][r];
                if constexpr (EP == 0) {
                    bf16* C = (bf16*)Cv;
                    const int b = m >> 11, s = m & 2047;
                    const int h = n >> 6,  d = n & 63;
                    C[(((size_t)(b * 16 + h)) * 2048 + s) * 64 + d] = (bf16)vv;
                } else if constexpr (EP == 1) {
                    float* C = (float*)Cv;
                    C[(size_t)m * 1024 + n] = vv;
                } else {
                    bf16* C = (bf16*)Cv;   // V^T: [b][h*64+d=m][s=n&2047]
                    C[((size_t)(n >> 11) * 1024 + m) * 2048 + (n & 2047)] = (bf16)vv;
                }
            }
        }
    }
}

// 768 blocks = 3/CU single pass at (256,3). LDS 32KB x3 = 96KB <= 160KB.
__global__ __launch_bounds__(256, 3) void qkv_bf(
    const bf16* __restrict__ Xq, const bf16* __restrict__ Xk,
    const bf16* __restrict__ Xv, const bf16* __restrict__ Wc,
    bf16* __restrict__ Qb, bf16* __restrict__ Kb, bf16* __restrict__ Vb) {
    const int z = blockIdx.z;
    if (z == 0)
        gemm_bf<0>(Xq, Wc, Qb, blockIdx.x * 128, blockIdx.y * 128);
    else if (z == 1)
        gemm_bf<0>(Xk, Wc + 1048576, Kb, blockIdx.x * 128, blockIdx.y * 128);
    else
        gemm_bf<2>(Wc + 2 * 1048576, Xv, Vb, blockIdx.y * 128, blockIdx.x * 128);
}

// ---------------------------------------------------------------------------
// out GEMM: 256 blocks, 512 threads / 8 waves, wave-tile 64x32, BK=32 with
// the same 2-phase double-buffer.
// ---------------------------------------------------------------------------
__global__ __launch_bounds__(512, 2) void out_gemm(
    const bf16* __restrict__ X, const bf16* __restrict__ W, float* __restrict__ C) {
    constexpr int K = 1024;
    __shared__ __align__(16) bf16 As[2][128 * 32];
    __shared__ __align__(16) bf16 Bs[2][128 * 32];

    const int t = threadIdx.x;
    const int lane = t & 63;
    const int w = t >> 6;            // 0..7
    const int wm = (w >> 2) * 64;    // 2 m-groups
    const int wn = (w & 3) * 32;     // 4 n-groups
    const int lr = lane & 15;
    const int lq8 = (lane >> 4) * 8;
    const int rq = (lane >> 4) * 4;
    const int m0 = blockIdx.x * 128, n0 = blockIdx.y * 128;

    f32x4 acc[4][2] = {};

    const int srow = t >> 2;         // 0..127 (one 16B chunk per thread)
    const int sch = (t & 3) * 8;
    char* lA = (char*)As;
    char* lB = (char*)Bs;

#define OSTAGE(buf, k0)                                                              \
    do {                                                                             \
        gl_lds16(X + (size_t)(m0 + srow) * K + (k0) + sch,                           \
                 lA + (buf) * 8192 + t * 16);                                        \
        gl_lds16(W + (size_t)(n0 + srow) * K + (k0) + sch,                           \
                 lB + (buf) * 8192 + t * 16);                                        \
    } while (0)

    OSTAGE(0, 0);
    __syncthreads();

    int cur = 0;
    for (int k0 = 0; k0 < K; k0 += 32) {
        if (k0 + 32 < K) OSTAGE(cur ^ 1, k0 + 32);

        bf16x8 af[4], bfr[2];
#pragma unroll
        for (int i = 0; i < 4; ++i)
            af[i] = *(const bf16x8*)&As[cur][(wm + i * 16 + lr) * 32 + lq8];
#pragma unroll
        for (int i = 0; i < 2; ++i)
            bfr[i] = *(const bf16x8*)&Bs[cur][(wn + i * 16 + lr) * 32 + lq8];
#pragma unroll
        for (int mi = 0; mi < 4; ++mi)
#pragma unroll
            for (int ni = 0; ni < 2; ++ni)
                acc[mi][ni] = MFMA16(af[mi], bfr[ni], acc[mi][ni]);

        __syncthreads();
        cur ^= 1;
    }
#undef OSTAGE

#pragma unroll
    for (int mi = 0; mi < 4; ++mi)
#pragma unroll
        for (int ni = 0; ni < 2; ++ni)
#pragma unroll
            for (int r = 0; r < 4; ++r) {
                const int m = m0 + wm + mi * 16 + rq + r;
                const int n = n0 + wn + ni * 16 + lr;
                C[(size_t)m * 1024 + n] = acc[mi][ni][r];
            }
}

// ---------------------------------------------------------------------------
// Fallback qkv (fp32 tokens staged in-register) for small workspaces.
// ---------------------------------------------------------------------------
template <int MODE>
__device__ __forceinline__ void gemm_f32tok(const void* __restrict__ Av,
                                            const void* __restrict__ Bv,
                                            bf16* __restrict__ C,
                                            const int m0, const int n0) {
    constexpr int K = 1024;
    __shared__ __align__(16) bf16 As[128 * 32];
    __shared__ __align__(16) bf16 Bs[128 * 32];

    const int t = threadIdx.x;
    const int lane = t & 63;
    const int w = t >> 6;
    const int wm = (w & 1) * 64;
    const int wn = (w >> 1) * 64;
    const int lr = lane & 15;
    const int lq8 = (lane >> 4) * 8;
    const int rq = (lane >> 4) * 4;

    f32x4 acc[4][4] = {};
    const int srow = t >> 2;
    const int sch = (t & 3) * 8;
    const int ar = t >> 1;
    const int ac = (t & 1) * 16;
    char* lA = (char*)As;
    char* lB = (char*)Bs;

    for (int k0 = 0; k0 < K; k0 += 32) {
        if constexpr (MODE == 0) {
            const float* X = (const float*)Av;
            const float* p = X + (size_t)(m0 + ar) * K + k0 + ac;
            float4 f0 = ((const float4*)p)[0], f1 = ((const float4*)p)[1];
            float4 f2 = ((const float4*)p)[2], f3 = ((const float4*)p)[3];
            bf16x8 o0, o1;
            o0[0]=(bf16)f0.x; o0[1]=(bf16)f0.y; o0[2]=(bf16)f0.z; o0[3]=(bf16)f0.w;
            o0[4]=(bf16)f1.x; o0[5]=(bf16)f1.y; o0[6]=(bf16)f1.z; o0[7]=(bf16)f1.w;
            o1[0]=(bf16)f2.x; o1[1]=(bf16)f2.y; o1[2]=(bf16)f2.z; o1[3]=(bf16)f2.w;
            o1[4]=(bf16)f3.x; o1[5]=(bf16)f3.y; o1[6]=(bf16)f3.z; o1[7]=(bf16)f3.w;
            *(bf16x8*)&As[ar * 32 + ac]     = o0;
            *(bf16x8*)&As[ar * 32 + ac + 8] = o1;
        } else {
            const bf16* X = (const bf16*)Av;
            gl_lds16(X + (size_t)(m0 + srow) * K + k0 + sch,      lA + t * 16);
            gl_lds16(X + (size_t)(m0 + 64 + srow) * K + k0 + sch, lA + 4096 + t * 16);
        }
        if constexpr (MODE == 2) {
            const float* X = (const float*)Bv;
            const float* p = X + (size_t)(n0 + ar) * K + k0 + ac;
            float4 f0 = ((const float4*)p)[0], f1 = ((const float4*)p)[1];
            float4 f2 = ((const float4*)p)[2], f3 = ((const float4*)p)[3];
            bf16x8 o0, o1;
            o0[0]=(bf16)f0.x; o0[1]=(bf16)f0.y; o0[2]=(bf16)f0.z; o0[3]=(bf16)f0.w;
            o0[4]=(bf16)f1.x; o0[5]=(bf16)f1.y; o0[6]=(bf16)f1.z; o0[7]=(bf16)f1.w;
            o1[0]=(bf16)f2.x; o1[1]=(bf16)f2.y; o1[2]=(bf16)f2.z; o1[3]=(bf16)f2.w;
            o1[4]=(bf16)f3.x; o1[5]=(bf16)f3.y; o1[6]=(bf16)f3.z; o1[7]=(bf16)f3.w;
            *(bf16x8*)&Bs[ar * 32 + ac]     = o0;
            *(bf16x8*)&Bs[ar * 32 + ac + 8] = o1;
        } else {
            const bf16* W = (const bf16*)Bv;
            gl_lds16(W + (size_t)(n0 + srow) * K + k0 + sch,      lB + t * 16);
            gl_lds16(W + (size_t)(n0 + 64 + srow) * K + k0 + sch, lB + 4096 + t * 16);
        }
        __syncthreads();

        bf16x8 af[4], bfr[4];
#pragma unroll
        for (int i = 0; i < 4; ++i) {
            af[i]  = *(const bf16x8*)&As[(wm + i * 16 + lr) * 32 + lq8];
            bfr[i] = *(const bf16x8*)&Bs[(wn + i * 16 + lr) * 32 + lq8];
        }
#pragma unroll
        for (int mi = 0; mi < 4; ++mi)
#pragma unroll
            for (int ni = 0; ni < 4; ++ni)
                acc[mi][ni] = MFMA16(af[mi], bfr[ni], acc[mi][ni]);
        __syncthreads();
    }

#pragma unroll
    for (int mi = 0; mi < 4; ++mi) {
#pragma unroll
        for (int ni = 0; ni < 4; ++ni) {
#pragma unroll
            for (int r = 0; r < 4; ++r) {
                const int m = m0 + wm + mi * 16 + rq + r;
                const int n = n0 + wn + ni * 16 + lr;
                const float vv = acc[mi][ni][r];
                if constexpr (MODE == 0) {
                    const int b = m >> 11, s = m & 2047;
                    const int h = n >> 6,  d = n & 63;
                    C[(((size_t)(b * 16 + h)) * 2048 + s) * 64 + d] = (bf16)vv;
                } else {
                    C[((size_t)(n >> 11) * 1024 + m) * 2048 + (n & 2047)] = (bf16)vv;
                }
            }
        }
    }
}

__global__ __launch_bounds__(256, 2) void qkv_f32(
    const float* __restrict__ q, const float* __restrict__ k, const float* __restrict__ v,
    const bf16* __restrict__ Wc, bf16* __restrict__ Qb, bf16* __restrict__ Kb,
    bf16* __restrict__ Vb) {
    const int z = blockIdx.z;
    if (z == 0)
        gemm_f32tok<0>(q, Wc, Qb, blockIdx.x * 128, blockIdx.y * 128);
    else if (z == 1)
        gemm_f32tok<0>(k, Wc + 1048576, Kb, blockIdx.x * 128, blockIdx.y * 128);
    else
        gemm_f32tok<2>(Wc + 2 * 1048576, v, Vb, blockIdx.y * 128, blockIdx.x * 128);
}

// ---------------------------------------------------------------------------
// Fused flash attention v6 (proven 61.7us): key-split waves, 8-wave blocks.
// wg = w&3 owns q-tile (32 q), kh = w>>2 owns key half (1024 keys).
// Grid 512 = 2 blocks/CU = 16 waves/CU. Fixed-max softmax => halves merge
// by addition (one LDS swap at epilogue). XCD-pinned head decode (lin%8).
// No setprio (R5: -26% in lockstep).
// ---------------------------------------------------------------------------
__global__ __launch_bounds__(512, 4) void attn_kernel(
    const bf16* __restrict__ Qb, const bf16* __restrict__ Kb,
    const bf16* __restrict__ Vb, bf16* __restrict__ Xb) {
    constexpr int S = 2048;

    __shared__ __align__(16) bf16 smem[17408];

    const int t = threadIdx.x;
    const int lane = t & 63;
    const int w = t >> 6;
    const int wg = w & 3;              // q-tile within block
    const int kh = w >> 2;             // key half
    const int l31 = lane & 31;
    const int half = lane >> 5;

    // XCD-aware decode: head pinned to lin%8
    const int lin = blockIdx.x;
    const int g = lin >> 3;
    const int bh = (lin & 7) + 8 * (g & 3);
    const int q0 = (g >> 2) * 128 + wg * 32;

    const bf16* Q  = Qb + (size_t)bh * S * 64;   // [s][d]
    const bf16* Kh = Kb + (size_t)bh * S * 64;   // [s][d]
    const bf16* Vh = Vb + (size_t)bh * 64 * S;   // [d][s]

    // Q fragments in registers (B operand), scaled into log2 domain.
    const float qscale = 0.125f * 1.4426950408889634f;
    bf16x8 qf[4];
#pragma unroll
    for (int c = 0; c < 4; ++c) {
        bf16x8 v0 = *(const bf16x8*)(Q + (size_t)(q0 + l31) * 64 + c * 16 + half * 8);
#pragma unroll
        for (int e = 0; e < 8; ++e) v0[e] = (bf16)((float)v0[e] * qscale);
        qf[c] = v0;
    }

    f32x16 od[2] = {};                 // O[q(reg-pattern)][d = dt*32 + l31]
    float ls0 = 0.f, ls1 = 0.f, ls2 = 0.f, ls3 = 0.f;

    // staging: 256 threads per half (th == kh), 2 chunks per tensor each.
    const int tt = t & 255;
    const int sr = tt >> 2;            // key (K) / d (V), 0..63
    const int sc = (tt & 3) * 2;       // chunk-pair base
    const bf16* pKg = Kh + ((size_t)kh * 1024 + sr) * 64 + sc * 8;   // += 4096/tile
    const bf16* pVg = Vh + (size_t)sr * S + kh * 1024 + sc * 8;      // += 64/tile
    bf16* KsH = smem + kh * 4096;
    bf16* VsH = smem + 8192 + kh * 4096;
    int wKo[2];
#pragma unroll
    for (int c = 0; c < 2; ++c)
        wKo[c] = (sr >> 1) * 128 + ((((sr & 1) << 3) + sc + c) ^ ((sr >> 1) & 15)) * 8;

    bf16x8 pk[2], pv[2];
#pragma unroll
    for (int c = 0; c < 2; ++c) {
        pk[c] = *(const bf16x8*)(pKg + c * 8);
        pv[c] = *(const bf16x8*)(pVg + c * 8);
    }

    // frag-read address helpers (elements)
    const int fbase = (l31 >> 1) * 128;
    const int fb8 = (l31 & 1) << 3;
    const int fsw = l31 >> 1;

    for (int j = 0; j < 16; ++j) {
        __syncthreads();  // (A) prev tile's reads done
#pragma unroll
        for (int c = 0; c < 2; ++c) {
            *(bf16x8*)&KsH[wKo[c]] = pk[c];
            *(bf16x8*)&VsH[wKo[c]] = pv[c];
        }
        __syncthreads();  // (B) staging visible

        // swapped QK^T: sacc[kt] = K-tile(kt) x Q  ->  P[q=l31][k=reg-pattern]
        f32x16 sacc[2] = {};
#pragma unroll
        for (int kt = 0; kt < 2; ++kt) {
#pragma unroll
            for (int c = 0; c < 4; ++c) {
                bf16x8 kf = *(const bf16x8*)
                    &KsH[kt * 2048 + fbase + ((fb8 + c * 2 + half) ^ fsw) * 8];
                sacc[kt] = MFMA32(kf, qf[c], sacc[kt]);
            }
        }

        // prefetch next K/V tile (hidden behind softmax + PV)
        if (j + 1 < 16) {
            pKg += 4096;
            pVg += 64;
#pragma unroll
            for (int c = 0; c < 2; ++c) {
                pk[c] = *(const bf16x8*)(pKg + c * 8);
                pv[c] = *(const bf16x8*)(pVg + c * 8);
            }
        }

        // per k-tile: exp2 in-register, l accumulate, build PA frags, PV
#pragma unroll
        for (int kt = 0; kt < 2; ++kt) {
            float ex[16];
#pragma unroll
            for (int r = 0; r < 16; ++r)
                ex[r] = exp2f(sacc[kt][r]);
            ls0 += ex[0] + ex[4] + ex[8]  + ex[12];
            ls1 += ex[1] + ex[5] + ex[9]  + ex[13];
            ls2 += ex[2] + ex[6] + ex[10] + ex[14];
            ls3 += ex[3] + ex[7] + ex[11] + ex[15];

            // T12: pa holds P[q=l31][key = khbase + kt*32 + c2*16 + half*8 + 0..7]
            unsigned pa[8];
#pragma unroll
            for (int c2 = 0; c2 < 2; ++c2) {
#pragma unroll
                for (int wd = 0; wd < 2; ++wd) {
                    unsigned x = cvt_pk_bf16(ex[c2 * 8 + wd * 2 + 0], ex[c2 * 8 + wd * 2 + 1]);
                    unsigned y = cvt_pk_bf16(ex[c2 * 8 + wd * 2 + 4], ex[c2 * 8 + wd * 2 + 5]);
                    asm("v_permlane32_swap_b32 %0, %1" : "+v"(x), "+v"(y));
                    pa[c2 * 4 + wd]     = x;
                    pa[c2 * 4 + wd + 2] = y;
                }
            }

            // PV: O[dt] += P(keys kt*32+c2*16) @ V^T rows dt*32+l31
#pragma unroll
            for (int c2 = 0; c2 < 2; ++c2) {
                u32x4 aw;
                aw[0] = pa[c2 * 4 + 0]; aw[1] = pa[c2 * 4 + 1];
                aw[2] = pa[c2 * 4 + 2]; aw[3] = pa[c2 * 4 + 3];
                bf16x8 ap = __builtin_bit_cast(bf16x8, aw);
#pragma unroll
                for (int dt = 0; dt < 2; ++dt) {
                    const int cgv = kt * 4 + c2 * 2 + half;
                    bf16x8 vf = *(const bf16x8*)
                        &VsH[dt * 2048 + fbase + ((fb8 + cgv) ^ fsw) * 8];
                    od[dt] = MFMA32(ap, vf, od[dt]);
                }
            }
        }
    }

    // ---- merge the two key halves ----
    float lsum = ls0 + ls1 + ls2 + ls3;
    float ltot = lsum + __shfl_xor(lsum, 32);   // per q=l31, this wave's keys

    __syncthreads();  // all PV LDS reads done before swap overwrite
    float* fsm = (float*)smem;
    const int so = (wg * 64 + lane) * 34;
    if (kh == 1) {
        fsm[so + 32] = ltot;
#pragma unroll
        for (int r = 0; r < 16; ++r) {
            fsm[so + r]      = od[0][r];
            fsm[so + 16 + r] = od[1][r];
        }
    }
    __syncthreads();
    if (kh == 0) {
        ltot += fsm[so + 32];
        const float inv = 1.f / fmaxf(ltot, 1e-30f);   // lane L: q = L&31
        const int b = bh >> 4, hh = bh & 15;
#pragma unroll
        for (int r = 0; r < 16; ++r) {
            const int qrow = (r & 3) + 8 * (r >> 2) + 4 * half;
            const float invr = __shfl(inv, qrow);
            const size_t base = ((size_t)(b * 2048 + q0 + qrow)) * 1024 + hh * 64;
            Xb[base + l31]      = (bf16)((od[0][r] + fsm[so + r]) * invr);
            Xb[base + 32 + l31] = (bf16)((od[1][r] + fsm[so + 16 + r]) * invr);
        }
    }
}

extern "C" void kernel_launch(void* const* d_in, const int* in_sizes, int n_in,
                              void* d_out, int out_size, void* d_ws, size_t ws_size,
                              hipStream_t stream) {
    const float* q  = (const float*)d_in[0];
    const float* k  = (const float*)d_in[1];
    const float* v  = (const float*)d_in[2];
    const float* wq = (const float*)d_in[4];
    const float* wk = (const float*)d_in[5];
    const float* wv = (const float*)d_in[6];
    const float* wo = (const float*)d_in[7];
    float* out = (float*)d_out;

    const bool big = ws_size >= (size_t)64 * 1024 * 1024;
    bf16* Wc = (bf16*)d_ws;
    const dim3 blk(256);

    if (big) {
        bf16* Xq = Wc + 4 * 1048576;
        bf16* Xk = Xq + 4194304;
        bf16* Xv = Xk + 4194304;
        bf16* Qb = Xv + 4194304;
        bf16* Kb = Qb + 4194304;
        bf16* Vb = Kb + 4194304;          // [2,16,64,2048] (V^T)
        bf16* Xb = Vb + 4194304;
        cvt7<<<dim3(2048, 7), blk, 0, stream>>>(wq, wk, wv, wo, q, k, v, Wc);
        qkv_bf<<<dim3(32, 8, 3), blk, 0, stream>>>(Xq, Xk, Xv, Wc, Qb, Kb, Vb);
        attn_kernel<<<dim3(512), dim3(512), 0, stream>>>(Qb, Kb, Vb, Xb);
        out_gemm<<<dim3(32, 8), dim3(512), 0, stream>>>(Xb, Wc + 3 * 1048576, out);
    } else {
        bf16* Qb = Wc + 4 * 1048576;
        bf16* Kb = Qb + 4194304;
        bf16* Vb = Kb + 4194304;
        bf16* Xb = Vb + 4194304;
        cvt7<<<dim3(512, 4), blk, 0, stream>>>(wq, wk, wv, wo, q, k, v, Wc);
        qkv_f32<<<dim3(32, 8, 3), blk, 0, stream>>>(q, k, v, Wc, Qb, Kb, Vb);
        attn_kernel<<<dim3(512), dim3(512), 0, stream>>>(Qb, Kb, Vb, Xb);
        out_gemm<<<dim3(32, 8), dim3(512), 0, stream>>>(Xb, Wc + 3 * 1048576, out);
    }
}

// Round 10
// 236.730 us; speedup vs baseline: 1.0577x; 1.0281x over previous
//
#include <hip/hip_runtime.h>
#include <hip/hip_bf16.h>
#include <math.h>

typedef __bf16 bf16;
typedef __bf16 bf16x8 __attribute__((ext_vector_type(8)));
typedef float f32x4 __attribute__((ext_vector_type(4)));
typedef float f32x16 __attribute__((ext_vector_type(16)));
typedef unsigned u32x4 __attribute__((ext_vector_type(4)));

#define MFMA16(a, b, c) __builtin_amdgcn_mfma_f32_16x16x32_bf16((a), (b), (c), 0, 0, 0)
#define MFMA32(a, b, c) __builtin_amdgcn_mfma_f32_32x32x16_bf16((a), (b), (c), 0, 0, 0)

// async global->LDS, 16B per lane. LDS dest = wave-uniform base + lane*16.
__device__ __forceinline__ void gl_lds16(const void* g, void* l) {
    __builtin_amdgcn_global_load_lds(
        (__attribute__((address_space(1))) void*)(g),
        (__attribute__((address_space(3))) void*)(l),
        16, 0, 0);
}

__device__ __forceinline__ unsigned cvt_pk_bf16(float lo, float hi) {
    unsigned r;
    asm("v_cvt_pk_bf16_f32 %0, %1, %2" : "=v"(r) : "v"(lo), "v"(hi));
    return r;
}

// ---------------------------------------------------------------------------
// fp32 -> bf16 conversion: 4 weights (1M) + optionally 3 token tensors (4M).
// ---------------------------------------------------------------------------
__global__ __launch_bounds__(256) void cvt7(
    const float* __restrict__ w0, const float* __restrict__ w1,
    const float* __restrict__ w2, const float* __restrict__ w3,
    const float* __restrict__ x0, const float* __restrict__ x1,
    const float* __restrict__ x2, bf16* __restrict__ dst) {
    const int z = blockIdx.y;
    const float* src;
    bf16* out;
    if (z < 4) {
        if (blockIdx.x >= 512) return;
        src = (z == 0) ? w0 : (z == 1) ? w1 : (z == 2) ? w2 : w3;
        out = dst + (size_t)z * 1048576;
    } else {
        src = (z == 4) ? x0 : (z == 5) ? x1 : x2;
        out = dst + 4 * 1048576 + (size_t)(z - 4) * 4194304;
    }
    const int i = (blockIdx.x * 256 + threadIdx.x) * 8;
    float4 a = ((const float4*)(src + i))[0];
    float4 b = ((const float4*)(src + i))[1];
    bf16x8 o;
    o[0] = (bf16)a.x; o[1] = (bf16)a.y; o[2] = (bf16)a.z; o[3] = (bf16)a.w;
    o[4] = (bf16)b.x; o[5] = (bf16)b.y; o[6] = (bf16)b.z; o[7] = (bf16)b.w;
    *(bf16x8*)(out + i) = o;
}

// ---------------------------------------------------------------------------
// Pure-bf16 GEMM, BK=32, 2-phase double-buffer. LDS is passed IN from the
// kernel (R8 lesson: __shared__ inside a template allocates per
// INSTANTIATION -- qkv_bf's two instantiations gave 64KB/block, capping
// occupancy at 2 blocks/CU; measured LDS_Block_Size 65536). Buffers: 16KB
// each of As[2][128*32], Bs[2][128*32] = 32KB total -> 3 blocks/CU.
// Accumulation order identical -> bit-identical results.
// EP 0: scatter bf16 -> [B,H,S,dk]   EP 1: fp32 [M,1024]   EP 2: V^T [B,H,dk,S]
// ---------------------------------------------------------------------------
template <int EP>
__device__ __forceinline__ void gemm_bf(const bf16* __restrict__ A,
                                        const bf16* __restrict__ B,
                                        void* __restrict__ Cv,
                                        const int m0, const int n0,
                                        bf16* __restrict__ As,
                                        bf16* __restrict__ Bs) {
    constexpr int K = 1024;

    const int t = threadIdx.x;
    const int lane = t & 63;
    const int w = t >> 6;
    const int wm = (w & 1) * 64;
    const int wn = (w >> 1) * 64;
    const int lr = lane & 15;
    const int lq8 = (lane >> 4) * 8;
    const int rq = (lane >> 4) * 4;

    f32x4 acc[4][4] = {};

    const int srow = t >> 2;
    const int sch = (t & 3) * 8;
    char* lA = (char*)As;
    char* lB = (char*)Bs;

#define QSTAGE(buf, k0)                                                              \
    do {                                                                             \
        gl_lds16(A + (size_t)(m0 + srow) * K + (k0) + sch,                           \
                 lA + (buf) * 8192 + t * 16);                                        \
        gl_lds16(A + (size_t)(m0 + 64 + srow) * K + (k0) + sch,                      \
                 lA + (buf) * 8192 + 4096 + t * 16);                                 \
        gl_lds16(B + (size_t)(n0 + srow) * K + (k0) + sch,                           \
                 lB + (buf) * 8192 + t * 16);                                        \
        gl_lds16(B + (size_t)(n0 + 64 + srow) * K + (k0) + sch,                      \
                 lB + (buf) * 8192 + 4096 + t * 16);                                 \
    } while (0)

    QSTAGE(0, 0);
    __syncthreads();   // buf0 ready

    int cur = 0;
    for (int k0 = 0; k0 < K; k0 += 32) {
        if (k0 + 32 < K) QSTAGE(cur ^ 1, k0 + 32);  // async, hidden by compute

        bf16x8 af[4], bfr[4];
#pragma unroll
        for (int i = 0; i < 4; ++i) {
            af[i]  = *(const bf16x8*)&As[cur * 4096 + (wm + i * 16 + lr) * 32 + lq8];
            bfr[i] = *(const bf16x8*)&Bs[cur * 4096 + (wn + i * 16 + lr) * 32 + lq8];
        }
#pragma unroll
        for (int mi = 0; mi < 4; ++mi)
#pragma unroll
            for (int ni = 0; ni < 4; ++ni)
                acc[mi][ni] = MFMA16(af[mi], bfr[ni], acc[mi][ni]);

        __syncthreads();   // drains staged loads + all reads of cur done
        cur ^= 1;
    }
#undef QSTAGE

#pragma unroll
    for (int mi = 0; mi < 4; ++mi) {
#pragma unroll
        for (int ni = 0; ni < 4; ++ni) {
#pragma unroll
            for (int r = 0; r < 4; ++r) {
                const int m = m0 + wm + mi * 16 + rq + r;
                const int n = n0 + wn + ni * 16 + lr;
                const float vv = acc[mi][ni][r];
                if constexpr (EP == 0) {
                    bf16* C = (bf16*)Cv;
                    const int b = m >> 11, s = m & 2047;
                    const int h = n >> 6,  d = n & 63;
                    C[(((size_t)(b * 16 + h)) * 2048 + s) * 64 + d] = (bf16)vv;
                } else if constexpr (EP == 1) {
                    float* C = (float*)Cv;
                    C[(size_t)m * 1024 + n] = vv;
                } else {
                    bf16* C = (bf16*)Cv;   // V^T: [b][h*64+d=m][s=n&2047]
                    C[((size_t)(n >> 11) * 1024 + m) * 2048 + (n & 2047)] = (bf16)vv;
                }
            }
        }
    }
}

// 768 blocks = 3/CU single pass at (256,3). LDS 32KB x3 = 96KB <= 160KB.
__global__ __launch_bounds__(256, 3) void qkv_bf(
    const bf16* __restrict__ Xq, const bf16* __restrict__ Xk,
    const bf16* __restrict__ Xv, const bf16* __restrict__ Wc,
    bf16* __restrict__ Qb, bf16* __restrict__ Kb, bf16* __restrict__ Vb) {
    __shared__ __align__(16) bf16 As[2 * 128 * 32];
    __shared__ __align__(16) bf16 Bs[2 * 128 * 32];
    const int z = blockIdx.z;
    if (z == 0)
        gemm_bf<0>(Xq, Wc, Qb, blockIdx.x * 128, blockIdx.y * 128, As, Bs);
    else if (z == 1)
        gemm_bf<0>(Xk, Wc + 1048576, Kb, blockIdx.x * 128, blockIdx.y * 128, As, Bs);
    else
        gemm_bf<2>(Wc + 2 * 1048576, Xv, Vb, blockIdx.y * 128, blockIdx.x * 128, As, Bs);
}

// ---------------------------------------------------------------------------
// out GEMM: 256 blocks, 512 threads / 8 waves, wave-tile 64x32, BK=32 with
// the same 2-phase double-buffer (single instantiation -> LDS already 32KB).
// ---------------------------------------------------------------------------
__global__ __launch_bounds__(512, 2) void out_gemm(
    const bf16* __restrict__ X, const bf16* __restrict__ W, float* __restrict__ C) {
    constexpr int K = 1024;
    __shared__ __align__(16) bf16 As[2][128 * 32];
    __shared__ __align__(16) bf16 Bs[2][128 * 32];

    const int t = threadIdx.x;
    const int lane = t & 63;
    const int w = t >> 6;            // 0..7
    const int wm = (w >> 2) * 64;    // 2 m-groups
    const int wn = (w & 3) * 32;     // 4 n-groups
    const int lr = lane & 15;
    const int lq8 = (lane >> 4) * 8;
    const int rq = (lane >> 4) * 4;
    const int m0 = blockIdx.x * 128, n0 = blockIdx.y * 128;

    f32x4 acc[4][2] = {};

    const int srow = t >> 2;         // 0..127 (one 16B chunk per thread)
    const int sch = (t & 3) * 8;
    char* lA = (char*)As;
    char* lB = (char*)Bs;

#define OSTAGE(buf, k0)                                                              \
    do {                                                                             \
        gl_lds16(X + (size_t)(m0 + srow) * K + (k0) + sch,                           \
                 lA + (buf) * 8192 + t * 16);                                        \
        gl_lds16(W + (size_t)(n0 + srow) * K + (k0) + sch,                           \
                 lB + (buf) * 8192 + t * 16);                                        \
    } while (0)

    OSTAGE(0, 0);
    __syncthreads();

    int cur = 0;
    for (int k0 = 0; k0 < K; k0 += 32) {
        if (k0 + 32 < K) OSTAGE(cur ^ 1, k0 + 32);

        bf16x8 af[4], bfr[2];
#pragma unroll
        for (int i = 0; i < 4; ++i)
            af[i] = *(const bf16x8*)&As[cur][(wm + i * 16 + lr) * 32 + lq8];
#pragma unroll
        for (int i = 0; i < 2; ++i)
            bfr[i] = *(const bf16x8*)&Bs[cur][(wn + i * 16 + lr) * 32 + lq8];
#pragma unroll
        for (int mi = 0; mi < 4; ++mi)
#pragma unroll
            for (int ni = 0; ni < 2; ++ni)
                acc[mi][ni] = MFMA16(af[mi], bfr[ni], acc[mi][ni]);

        __syncthreads();
        cur ^= 1;
    }
#undef OSTAGE

#pragma unroll
    for (int mi = 0; mi < 4; ++mi)
#pragma unroll
        for (int ni = 0; ni < 2; ++ni)
#pragma unroll
            for (int r = 0; r < 4; ++r) {
                const int m = m0 + wm + mi * 16 + rq + r;
                const int n = n0 + wn + ni * 16 + lr;
                C[(size_t)m * 1024 + n] = acc[mi][ni][r];
            }
}

// ---------------------------------------------------------------------------
// Fallback qkv (fp32 tokens staged in-register) for small workspaces.
// LDS hoisted to kernel (same duplication hazard).
// ---------------------------------------------------------------------------
template <int MODE>
__device__ __forceinline__ void gemm_f32tok(const void* __restrict__ Av,
                                            const void* __restrict__ Bv,
                                            bf16* __restrict__ C,
                                            const int m0, const int n0,
                                            bf16* __restrict__ As,
                                            bf16* __restrict__ Bs) {
    constexpr int K = 1024;

    const int t = threadIdx.x;
    const int lane = t & 63;
    const int w = t >> 6;
    const int wm = (w & 1) * 64;
    const int wn = (w >> 1) * 64;
    const int lr = lane & 15;
    const int lq8 = (lane >> 4) * 8;
    const int rq = (lane >> 4) * 4;

    f32x4 acc[4][4] = {};
    const int srow = t >> 2;
    const int sch = (t & 3) * 8;
    const int ar = t >> 1;
    const int ac = (t & 1) * 16;
    char* lA = (char*)As;
    char* lB = (char*)Bs;

    for (int k0 = 0; k0 < K; k0 += 32) {
        if constexpr (MODE == 0) {
            const float* X = (const float*)Av;
            const float* p = X + (size_t)(m0 + ar) * K + k0 + ac;
            float4 f0 = ((const float4*)p)[0], f1 = ((const float4*)p)[1];
            float4 f2 = ((const float4*)p)[2], f3 = ((const float4*)p)[3];
            bf16x8 o0, o1;
            o0[0]=(bf16)f0.x; o0[1]=(bf16)f0.y; o0[2]=(bf16)f0.z; o0[3]=(bf16)f0.w;
            o0[4]=(bf16)f1.x; o0[5]=(bf16)f1.y; o0[6]=(bf16)f1.z; o0[7]=(bf16)f1.w;
            o1[0]=(bf16)f2.x; o1[1]=(bf16)f2.y; o1[2]=(bf16)f2.z; o1[3]=(bf16)f2.w;
            o1[4]=(bf16)f3.x; o1[5]=(bf16)f3.y; o1[6]=(bf16)f3.z; o1[7]=(bf16)f3.w;
            *(bf16x8*)&As[ar * 32 + ac]     = o0;
            *(bf16x8*)&As[ar * 32 + ac + 8] = o1;
        } else {
            const bf16* X = (const bf16*)Av;
            gl_lds16(X + (size_t)(m0 + srow) * K + k0 + sch,      lA + t * 16);
            gl_lds16(X + (size_t)(m0 + 64 + srow) * K + k0 + sch, lA + 4096 + t * 16);
        }
        if constexpr (MODE == 2) {
            const float* X = (const float*)Bv;
            const float* p = X + (size_t)(n0 + ar) * K + k0 + ac;
            float4 f0 = ((const float4*)p)[0], f1 = ((const float4*)p)[1];
            float4 f2 = ((const float4*)p)[2], f3 = ((const float4*)p)[3];
            bf16x8 o0, o1;
            o0[0]=(bf16)f0.x; o0[1]=(bf16)f0.y; o0[2]=(bf16)f0.z; o0[3]=(bf16)f0.w;
            o0[4]=(bf16)f1.x; o0[5]=(bf16)f1.y; o0[6]=(bf16)f1.z; o0[7]=(bf16)f1.w;
            o1[0]=(bf16)f2.x; o1[1]=(bf16)f2.y; o1[2]=(bf16)f2.z; o1[3]=(bf16)f2.w;
            o1[4]=(bf16)f3.x; o1[5]=(bf16)f3.y; o1[6]=(bf16)f3.z; o1[7]=(bf16)f3.w;
            *(bf16x8*)&Bs[ar * 32 + ac]     = o0;
            *(bf16x8*)&Bs[ar * 32 + ac + 8] = o1;
        } else {
            const bf16* W = (const bf16*)Bv;
            gl_lds16(W + (size_t)(n0 + srow) * K + k0 + sch,      lB + t * 16);
            gl_lds16(W + (size_t)(n0 + 64 + srow) * K + k0 + sch, lB + 4096 + t * 16);
        }
        __syncthreads();

        bf16x8 af[4], bfr[4];
#pragma unroll
        for (int i = 0; i < 4; ++i) {
            af[i]  = *(const bf16x8*)&As[(wm + i * 16 + lr) * 32 + lq8];
            bfr[i] = *(const bf16x8*)&Bs[(wn + i * 16 + lr) * 32 + lq8];
        }
#pragma unroll
        for (int mi = 0; mi < 4; ++mi)
#pragma unroll
            for (int ni = 0; ni < 4; ++ni)
                acc[mi][ni] = MFMA16(af[mi], bfr[ni], acc[mi][ni]);
        __syncthreads();
    }

#pragma unroll
    for (int mi = 0; mi < 4; ++mi) {
#pragma unroll
        for (int ni = 0; ni < 4; ++ni) {
#pragma unroll
            for (int r = 0; r < 4; ++r) {
                const int m = m0 + wm + mi * 16 + rq + r;
                const int n = n0 + wn + ni * 16 + lr;
                const float vv = acc[mi][ni][r];
                if constexpr (MODE == 0) {
                    const int b = m >> 11, s = m & 2047;
                    const int h = n >> 6,  d = n & 63;
                    C[(((size_t)(b * 16 + h)) * 2048 + s) * 64 + d] = (bf16)vv;
                } else {
                    C[((size_t)(n >> 11) * 1024 + m) * 2048 + (n & 2047)] = (bf16)vv;
                }
            }
        }
    }
}

__global__ __launch_bounds__(256, 2) void qkv_f32(
    const float* __restrict__ q, const float* __restrict__ k, const float* __restrict__ v,
    const bf16* __restrict__ Wc, bf16* __restrict__ Qb, bf16* __restrict__ Kb,
    bf16* __restrict__ Vb) {
    __shared__ __align__(16) bf16 As[128 * 32];
    __shared__ __align__(16) bf16 Bs[128 * 32];
    const int z = blockIdx.z;
    if (z == 0)
        gemm_f32tok<0>(q, Wc, Qb, blockIdx.x * 128, blockIdx.y * 128, As, Bs);
    else if (z == 1)
        gemm_f32tok<0>(k, Wc + 1048576, Kb, blockIdx.x * 128, blockIdx.y * 128, As, Bs);
    else
        gemm_f32tok<2>(Wc + 2 * 1048576, v, Vb, blockIdx.y * 128, blockIdx.x * 128, As, Bs);
}

// ---------------------------------------------------------------------------
// Fused flash attention v6 (proven 61.7us): key-split waves, 8-wave blocks.
// wg = w&3 owns q-tile (32 q), kh = w>>2 owns key half (1024 keys).
// Grid 512 = 2 blocks/CU = 16 waves/CU. Fixed-max softmax => halves merge
// by addition (one LDS swap at epilogue). XCD-pinned head decode (lin%8).
// No setprio (R5: -26% in lockstep).
// ---------------------------------------------------------------------------
__global__ __launch_bounds__(512, 4) void attn_kernel(
    const bf16* __restrict__ Qb, const bf16* __restrict__ Kb,
    const bf16* __restrict__ Vb, bf16* __restrict__ Xb) {
    constexpr int S = 2048;

    __shared__ __align__(16) bf16 smem[17408];

    const int t = threadIdx.x;
    const int lane = t & 63;
    const int w = t >> 6;
    const int wg = w & 3;              // q-tile within block
    const int kh = w >> 2;             // key half
    const int l31 = lane & 31;
    const int half = lane >> 5;

    // XCD-aware decode: head pinned to lin%8
    const int lin = blockIdx.x;
    const int g = lin >> 3;
    const int bh = (lin & 7) + 8 * (g & 3);
    const int q0 = (g >> 2) * 128 + wg * 32;

    const bf16* Q  = Qb + (size_t)bh * S * 64;   // [s][d]
    const bf16* Kh = Kb + (size_t)bh * S * 64;   // [s][d]
    const bf16* Vh = Vb + (size_t)bh * 64 * S;   // [d][s]

    // Q fragments in registers (B operand), scaled into log2 domain.
    const float qscale = 0.125f * 1.4426950408889634f;
    bf16x8 qf[4];
#pragma unroll
    for (int c = 0; c < 4; ++c) {
        bf16x8 v0 = *(const bf16x8*)(Q + (size_t)(q0 + l31) * 64 + c * 16 + half * 8);
#pragma unroll
        for (int e = 0; e < 8; ++e) v0[e] = (bf16)((float)v0[e] * qscale);
        qf[c] = v0;
    }

    f32x16 od[2] = {};                 // O[q(reg-pattern)][d = dt*32 + l31]
    float ls0 = 0.f, ls1 = 0.f, ls2 = 0.f, ls3 = 0.f;

    // staging: 256 threads per half (th == kh), 2 chunks per tensor each.
    const int tt = t & 255;
    const int sr = tt >> 2;            // key (K) / d (V), 0..63
    const int sc = (tt & 3) * 2;       // chunk-pair base
    const bf16* pKg = Kh + ((size_t)kh * 1024 + sr) * 64 + sc * 8;   // += 4096/tile
    const bf16* pVg = Vh + (size_t)sr * S + kh * 1024 + sc * 8;      // += 64/tile
    bf16* KsH = smem + kh * 4096;
    bf16* VsH = smem + 8192 + kh * 4096;
    int wKo[2];
#pragma unroll
    for (int c = 0; c < 2; ++c)
        wKo[c] = (sr >> 1) * 128 + ((((sr & 1) << 3) + sc + c) ^ ((sr >> 1) & 15)) * 8;

    bf16x8 pk[2], pv[2];
#pragma unroll
    for (int c = 0; c < 2; ++c) {
        pk[c] = *(const bf16x8*)(pKg + c * 8);
        pv[c] = *(const bf16x8*)(pVg + c * 8);
    }

    // frag-read address helpers (elements)
    const int fbase = (l31 >> 1) * 128;
    const int fb8 = (l31 & 1) << 3;
    const int fsw = l31 >> 1;

    for (int j = 0; j < 16; ++j) {
        __syncthreads();  // (A) prev tile's reads done
#pragma unroll
        for (int c = 0; c < 2; ++c) {
            *(bf16x8*)&KsH[wKo[c]] = pk[c];
            *(bf16x8*)&VsH[wKo[c]] = pv[c];
        }
        __syncthreads();  // (B) staging visible

        // swapped QK^T: sacc[kt] = K-tile(kt) x Q  ->  P[q=l31][k=reg-pattern]
        f32x16 sacc[2] = {};
#pragma unroll
        for (int kt = 0; kt < 2; ++kt) {
#pragma unroll
            for (int c = 0; c < 4; ++c) {
                bf16x8 kf = *(const bf16x8*)
                    &KsH[kt * 2048 + fbase + ((fb8 + c * 2 + half) ^ fsw) * 8];
                sacc[kt] = MFMA32(kf, qf[c], sacc[kt]);
            }
        }

        // prefetch next K/V tile (hidden behind softmax + PV)
        if (j + 1 < 16) {
            pKg += 4096;
            pVg += 64;
#pragma unroll
            for (int c = 0; c < 2; ++c) {
                pk[c] = *(const bf16x8*)(pKg + c * 8);
                pv[c] = *(const bf16x8*)(pVg + c * 8);
            }
        }

        // per k-tile: exp2 in-register, l accumulate, build PA frags, PV
#pragma unroll
        for (int kt = 0; kt < 2; ++kt) {
            float ex[16];
#pragma unroll
            for (int r = 0; r < 16; ++r)
                ex[r] = exp2f(sacc[kt][r]);
            ls0 += ex[0] + ex[4] + ex[8]  + ex[12];
            ls1 += ex[1] + ex[5] + ex[9]  + ex[13];
            ls2 += ex[2] + ex[6] + ex[10] + ex[14];
            ls3 += ex[3] + ex[7] + ex[11] + ex[15];

            // T12: pa holds P[q=l31][key = khbase + kt*32 + c2*16 + half*8 + 0..7]
            unsigned pa[8];
#pragma unroll
            for (int c2 = 0; c2 < 2; ++c2) {
#pragma unroll
                for (int wd = 0; wd < 2; ++wd) {
                    unsigned x = cvt_pk_bf16(ex[c2 * 8 + wd * 2 + 0], ex[c2 * 8 + wd * 2 + 1]);
                    unsigned y = cvt_pk_bf16(ex[c2 * 8 + wd * 2 + 4], ex[c2 * 8 + wd * 2 + 5]);
                    asm("v_permlane32_swap_b32 %0, %1" : "+v"(x), "+v"(y));
                    pa[c2 * 4 + wd]     = x;
                    pa[c2 * 4 + wd + 2] = y;
                }
            }

            // PV: O[dt] += P(keys kt*32+c2*16) @ V^T rows dt*32+l31
#pragma unroll
            for (int c2 = 0; c2 < 2; ++c2) {
                u32x4 aw;
                aw[0] = pa[c2 * 4 + 0]; aw[1] = pa[c2 * 4 + 1];
                aw[2] = pa[c2 * 4 + 2]; aw[3] = pa[c2 * 4 + 3];
                bf16x8 ap = __builtin_bit_cast(bf16x8, aw);
#pragma unroll
                for (int dt = 0; dt < 2; ++dt) {
                    const int cgv = kt * 4 + c2 * 2 + half;
                    bf16x8 vf = *(const bf16x8*)
                        &VsH[dt * 2048 + fbase + ((fb8 + cgv) ^ fsw) * 8];
                    od[dt] = MFMA32(ap, vf, od[dt]);
                }
            }
        }
    }

    // ---- merge the two key halves ----
    float lsum = ls0 + ls1 + ls2 + ls3;
    float ltot = lsum + __shfl_xor(lsum, 32);   // per q=l31, this wave's keys

    __syncthreads();  // all PV LDS reads done before swap overwrite
    float* fsm = (float*)smem;
    const int so = (wg * 64 + lane) * 34;
    if (kh == 1) {
        fsm[so + 32] = ltot;
#pragma unroll
        for (int r = 0; r < 16; ++r) {
            fsm[so + r]      = od[0][r];
            fsm[so + 16 + r] = od[1][r];
        }
    }
    __syncthreads();
    if (kh == 0) {
        ltot += fsm[so + 32];
        const float inv = 1.f / fmaxf(ltot, 1e-30f);   // lane L: q = L&31
        const int b = bh >> 4, hh = bh & 15;
#pragma unroll
        for (int r = 0; r < 16; ++r) {
            const int qrow = (r & 3) + 8 * (r >> 2) + 4 * half;
            const float invr = __shfl(inv, qrow);
            const size_t base = ((size_t)(b * 2048 + q0 + qrow)) * 1024 + hh * 64;
            Xb[base + l31]      = (bf16)((od[0][r] + fsm[so + r]) * invr);
            Xb[base + 32 + l31] = (bf16)((od[1][r] + fsm[so + 16 + r]) * invr);
        }
    }
}

extern "C" void kernel_launch(void* const* d_in, const int* in_sizes, int n_in,
                              void* d_out, int out_size, void* d_ws, size_t ws_size,
                              hipStream_t stream) {
    const float* q  = (const float*)d_in[0];
    const float* k  = (const float*)d_in[1];
    const float* v  = (const float*)d_in[2];
    const float* wq = (const float*)d_in[4];
    const float* wk = (const float*)d_in[5];
    const float* wv = (const float*)d_in[6];
    const float* wo = (const float*)d_in[7];
    float* out = (float*)d_out;

    const bool big = ws_size >= (size_t)64 * 1024 * 1024;
    bf16* Wc = (bf16*)d_ws;
    const dim3 blk(256);

    if (big) {
        bf16* Xq = Wc + 4 * 1048576;
        bf16* Xk = Xq + 4194304;
        bf16* Xv = Xk + 4194304;
        bf16* Qb = Xv + 4194304;
        bf16* Kb = Qb + 4194304;
        bf16* Vb = Kb + 4194304;          // [2,16,64,2048] (V^T)
        bf16* Xb = Vb + 4194304;
        cvt7<<<dim3(2048, 7), blk, 0, stream>>>(wq, wk, wv, wo, q, k, v, Wc);
        qkv_bf<<<dim3(32, 8, 3), blk, 0, stream>>>(Xq, Xk, Xv, Wc, Qb, Kb, Vb);
        attn_kernel<<<dim3(512), dim3(512), 0, stream>>>(Qb, Kb, Vb, Xb);
        out_gemm<<<dim3(32, 8), dim3(512), 0, stream>>>(Xb, Wc + 3 * 1048576, out);
    } else {
        bf16* Qb = Wc + 4 * 1048576;
        bf16* Kb = Qb + 4194304;
        bf16* Vb = Kb + 4194304;
        bf16* Xb = Vb + 4194304;
        cvt7<<<dim3(512, 4), blk, 0, stream>>>(wq, wk, wv, wo, q, k, v, Wc);
        qkv_f32<<<dim3(32, 8, 3), blk, 0, stream>>>(q, k, v, Wc, Qb, Kb, Vb);
        attn_kernel<<<dim3(512), dim3(512), 0, stream>>>(Qb, Kb, Vb, Xb);
        out_gemm<<<dim3(32, 8), dim3(512), 0, stream>>>(Xb, Wc + 3 * 1048576, out);
    }
}